// Round 15
// baseline (82.903 us; speedup 1.0000x reference)
//
#include <hip/hip_runtime.h>
#include <hip/hip_bf16.h>

typedef __hip_bfloat16 bf16;
typedef float in_t;
typedef float out_t;
typedef __attribute__((ext_vector_type(8))) short short8;   // 8 bf16 MFMA operand
typedef __attribute__((ext_vector_type(4))) float f32x4;    // MFMA accumulator

#define CH    64
#define CIN1  32
#define CIN2  64
#define S1    186624   // 36*72*72
#define W1    5184     // 72*72
#define S2    23328    // 18*36*36
#define W2    1296     // 36*36
#define LDSTR 1297     // k_M LDS row stride (coprime with 32)
#define BSTR  104      // k_corr patch lds bf16 row stride
#define OSTR  136      // proj_x output tile ushort stride
#define YSTR  68       // proj_y output tile ushort stride
#define HWSTR 76       // pool LDS row stride
#define INV_NZ (1.0f/(288.0f + 1e-5f))

#define NB_PL 2304     // pool blocks (half-planes)
#define NB_PX 1458     // proj_x blocks
#define NB_PY 365      // proj_y blocks (4 wave-tiles each)

static __device__ __forceinline__ unsigned short f2bu(float f) {
    bf16 h = __float2bfloat16(f);
    unsigned short u;
    __builtin_memcpy(&u, &h, 2);
    return u;
}
static __device__ __forceinline__ float bu2f(unsigned short u) {
    unsigned int v = ((unsigned int)u) << 16;
    float f;
    __builtin_memcpy(&f, &v, 4);
    return f;
}

// ---- fused stage 1: pool | proj_x (MFMA, direct-global frags) | proj_y (MFMA)
__global__ __launch_bounds__(256) void k_stage1(
    const in_t* __restrict__ x, const in_t* __restrict__ wi, const in_t* __restrict__ bi,
    bf16* __restrict__ xq,
    const in_t* __restrict__ y, const in_t* __restrict__ wf, const in_t* __restrict__ bf,
    unsigned short* __restrict__ yk,
    const in_t* __restrict__ z, unsigned short* __restrict__ xd)
{
    __shared__ __align__(16) char smem[17408];   // max(pool 11248, px ot 17408, py ot 8704)
    int bid = blockIdx.x;
    int t   = threadIdx.x;

    if (bid < NB_PL) {
        // ---- pool half-plane: AvgPool3d k3 s2 p1 cip=False, register d-sum + LDS hw
        float* dsum = reinterpret_cast<float*>(smem);
        int c  = bid / 36;
        int rr = bid - c*36;
        int od = rr >> 1, half = rr & 1;
        int hbase = half ? 35 : 0;
        int nrows = half ? 37 : 36;
        int oh0   = half ? 18 : 0;
        int dlo = od ? 2*od - 1 : 0;
        int nd  = od ? 3 : 2;
        const float* zb = z + ((size_t)c*36 + dlo)*W1;
        for (int i = t; i < nrows*18; i += 256) {
            int r = i / 18, q = i - (i/18)*18;
            int off = (hbase + r)*18 + q;
            const float4* p0 = reinterpret_cast<const float4*>(zb);
            float4 a = p0[off], b = p0[1296 + off];
            float4 s;
            if (nd == 3) {
                float4 e = p0[2592 + off];
                s = (float4){ a.x+b.x+e.x, a.y+b.y+e.y, a.z+b.z+e.z, a.w+b.w+e.w };
            } else {
                s = (float4){ a.x+b.x, a.y+b.y, a.z+b.z, a.w+b.w };
            }
            *reinterpret_cast<float4*>(&dsum[r*HWSTR + q*4]) = s;
        }
        __syncthreads();
        float icd = (nd == 3) ? (1.f/3.f) : 0.5f;
        unsigned short* xdp = xd + (size_t)c*S2 + (size_t)od*W2 + oh0*36;
        for (int idx = t; idx < 648; idx += 256) {
            int ohl = idx / 36, ow = idx - (idx/36)*36;
            int oh = oh0 + ohl;
            int h0 = oh ? 2*oh-1 : 0, h1 = 2*oh+1;
            int w0 = ow ? 2*ow-1 : 0, w1 = 2*ow+1;
            float s = 0.f;
            for (int h = h0; h <= h1; ++h) {
                int lr = h - hbase;
                for (int w = w0; w <= w1; ++w)
                    s += dsum[lr*HWSTR + w];
            }
            float ich = (h1 - h0) == 1 ? 0.5f : (1.f/3.f);
            float icw = (w1 - w0) == 1 ? 0.5f : (1.f/3.f);
            xdp[idx] = f2bu(s * icd * ich * icw);
        }
    } else if (bid < NB_PL + NB_PX) {
        // ---- proj_x: xq(64,S1) = Wi(64,32) x x(32,S1) + bi, bf16 out
        // fragments direct from global (proj_y pattern); LDS only for output restage
        int gs0 = (bid - NB_PL)*128;
        int l = t & 63, wv = t >> 6;
        int lcol = l & 15, loct = l >> 4;

        ushort4 rr[2][4];
        #pragma unroll
        for (int mt = 0; mt < 2; ++mt) {
            int scol = gs0 + (wv*2 + mt)*16 + lcol;
            union { short8 v; unsigned short u[8]; } af;
            #pragma unroll
            for (int j = 0; j < 8; ++j)
                af.u[j] = f2bu(x[(size_t)(loct*8 + j)*S1 + scol]);
            #pragma unroll
            for (int og = 0; og < 4; ++og) {
                int o = og*16 + lcol;
                union { short8 v; unsigned short u[8]; } wfr;
                float4 a  = *reinterpret_cast<const float4*>(&wi[o*CIN1 + loct*8]);
                float4 bq = *reinterpret_cast<const float4*>(&wi[o*CIN1 + loct*8 + 4]);
                wfr.u[0]=f2bu(a.x);  wfr.u[1]=f2bu(a.y);
                wfr.u[2]=f2bu(a.z);  wfr.u[3]=f2bu(a.w);
                wfr.u[4]=f2bu(bq.x); wfr.u[5]=f2bu(bq.y);
                wfr.u[6]=f2bu(bq.z); wfr.u[7]=f2bu(bq.w);
                float bo = bi[o];
                f32x4 d = { bo, bo, bo, bo };
                d = __builtin_amdgcn_mfma_f32_16x16x32_bf16(af.v, wfr.v, d, 0, 0, 0);
                rr[mt][og] = (ushort4){ f2bu(d[0]), f2bu(d[1]), f2bu(d[2]), f2bu(d[3]) };
            }
        }
        unsigned short* ot = reinterpret_cast<unsigned short*>(smem);  // 64 x OSTR
        #pragma unroll
        for (int mt = 0; mt < 2; ++mt)
            #pragma unroll
            for (int og = 0; og < 4; ++og)
                *reinterpret_cast<ushort4*>(
                    &ot[(og*16 + lcol)*OSTR + wv*32 + mt*16 + loct*4]) = rr[mt][og];
        __syncthreads();
        #pragma unroll
        for (int j = 0; j < 4; ++j) {
            int row = wv*16 + j*4 + (l >> 4);
            int c8  = l & 15;
            uint4 v = *reinterpret_cast<const uint4*>(&ot[row*OSTR + c8*8]);
            *reinterpret_cast<uint4*>(
                (unsigned short*)xq + (size_t)row*S1 + gs0 + c8*8) = v;
        }
    } else {
        // ---- proj_y: yk(64,S2) = Wf(64,64) x y(64,S2) + bf, bf16 out
        int pyb   = bid - NB_PL - NB_PX;
        int sblk0 = pyb*64;
        int wv = t >> 6, l = t & 63;
        int lcol = l & 15, loct = l >> 4;
        int tile = pyb*4 + wv;
        unsigned short* ot = reinterpret_cast<unsigned short*>(smem);   // 64 x YSTR
        if (tile < 1458) {
            int s0 = tile*16;
            union { short8 v; unsigned short u[8]; } af[2];
            #pragma unroll
            for (int kk = 0; kk < 2; ++kk)
                #pragma unroll
                for (int j = 0; j < 8; ++j)
                    af[kk].u[j] = f2bu(y[(size_t)(kk*32 + loct*8 + j)*S2 + s0 + lcol]);
            #pragma unroll
            for (int og = 0; og < 4; ++og) {
                int o = og*16 + lcol;
                union { short8 v; unsigned short u[8]; } wfr[2];
                #pragma unroll
                for (int kk = 0; kk < 2; ++kk) {
                    float4 a  = *reinterpret_cast<const float4*>(&wf[o*CIN2 + kk*32 + loct*8]);
                    float4 bq = *reinterpret_cast<const float4*>(&wf[o*CIN2 + kk*32 + loct*8 + 4]);
                    wfr[kk].u[0]=f2bu(a.x);  wfr[kk].u[1]=f2bu(a.y);
                    wfr[kk].u[2]=f2bu(a.z);  wfr[kk].u[3]=f2bu(a.w);
                    wfr[kk].u[4]=f2bu(bq.x); wfr[kk].u[5]=f2bu(bq.y);
                    wfr[kk].u[6]=f2bu(bq.z); wfr[kk].u[7]=f2bu(bq.w);
                }
                float bo = bf[o];
                f32x4 d = { bo, bo, bo, bo };
                d = __builtin_amdgcn_mfma_f32_16x16x32_bf16(af[0].v, wfr[0].v, d, 0, 0, 0);
                d = __builtin_amdgcn_mfma_f32_16x16x32_bf16(af[1].v, wfr[1].v, d, 0, 0, 0);
                ushort4 r4 = { f2bu(d[0]), f2bu(d[1]), f2bu(d[2]), f2bu(d[3]) };
                *reinterpret_cast<ushort4*>(&ot[(og*16 + lcol)*YSTR + wv*16 + loct*4]) = r4;
            }
        }
        __syncthreads();
        #pragma unroll
        for (int j = 0; j < 4; ++j) {
            int row = wv*16 + j*4 + (l >> 4);
            int c4  = l & 15;
            int s   = sblk0 + c4*4;
            if (s < S2) {
                ushort4 v = *reinterpret_cast<const ushort4*>(&ot[row*YSTR + c4*4]);
                *reinterpret_cast<ushort4*>(&yk[(size_t)row*S2 + s]) = v;
            }
        }
    }
}

// ---- M[c,k1,k2] = sum_m Uxd[c,k1,m]*Uy[c,k2,m]; bf16 in, bf16 zero-padded [c][96][96] out
__global__ __launch_bounds__(256) void k_M(
    const unsigned short* __restrict__ xd, const unsigned short* __restrict__ yk,
    unsigned short* __restrict__ Mg)
{
    __shared__ float xl[3*LDSTR];
    __shared__ float yl[3*LDSTR];
    int b = blockIdx.x;
    int c = b / 9, r = b - c*9;
    int g = r / 3, h = r - g*3;
    int t = threadIdx.x;
    int t1 = t / 27, t2 = t - (t/27)*27;
    int offx[3];
    #pragma unroll
    for (int a = 0; a < 3; ++a) {
        int kl = t1*3 + a;
        offx[a] = (kl/9)*LDSTR + (kl - (kl/9)*9);
    }
    int offy = (t2/9)*LDSTR + (t2 - (t2/9)*9);
    float acc[3] = {};
    for (int ph2 = 0; ph2 < 2; ++ph2) {
        __syncthreads();
        for (int idx = t; idx < 3*W2; idx += 256) {
            int rr = idx / W2, col = idx - rr*W2;
            xl[rr*LDSTR + col] = bu2f(xd[c*S2 + (ph2*9 + g*3 + rr)*W2 + col]);
            yl[rr*LDSTR + col] = bu2f(yk[c*S2 + (ph2*9 + h*3 + rr)*W2 + col]);
        }
        __syncthreads();
        if (t < 243) {
            for (int m = 0; m < 144; ++m) {
                int cb = m*9;
                float yv = yl[cb + offy];
                #pragma unroll
                for (int a = 0; a < 3; ++a)
                    acc[a] += xl[cb + offx[a]] * yv;
            }
        }
    }
    if (t < 243) {
        #pragma unroll
        for (int a = 0; a < 3; ++a) {
            int k1 = g*27 + t1*3 + a;
            Mg[c*9216 + k1*96 + (h*27 + t2)] = f2bu(acc[a]);
        }
    }
    if (r == 0) {
        for (int idx = t; idx < 2655; idx += 256) {
            int row, col;
            if (idx < 1440) { int q = idx/96; row = 81 + q; col = idx - q*96; }
            else { int j = idx - 1440; int q = j/15; row = q; col = 81 + (j - q*15); }
            Mg[c*9216 + row*96 + col] = 0;
        }
    }
}

// ---- MFMA corr: per (channel, 192-patch chunk): C(96x192) = Mg(96x96,bf16) x Uxq^T
__global__ __launch_bounds__(256, 4) void k_corr(
    const unsigned short* __restrict__ Mg, const bf16* __restrict__ xq,
    const in_t* __restrict__ z, out_t* __restrict__ out)
{
    __shared__ __align__(16) unsigned short Pl[192*BSTR];   // 39936 B -> 4 blocks/CU
    int bid = blockIdx.x;
    int c   = bid / 12;
    int rem = bid - c*12;
    int ph  = rem / 3;
    int ck  = rem - ph*3;
    int colbase = ck*1728;
    int t = threadIdx.x;

    for (int idx = t; idx < 192*15; idx += 256) {
        int r = idx/15;
        Pl[r*BSTR + 81 + (idx - r*15)] = 0;
    }
    const unsigned short* xqu =
        (const unsigned short*)(xq + (size_t)c*S1 + (size_t)(ph*9)*W1 + colbase);
    for (int idx = t; idx < 3888; idx += 256) {
        int i2 = idx / 432, v4 = idx - i2*432;
        ushort4 vv = *reinterpret_cast<const ushort4*>(xqu + (size_t)i2*W1 + v4*4);
        int col = v4*4;
        unsigned short uu[4] = {vv.x, vv.y, vv.z, vv.w};
        #pragma unroll
        for (int j = 0; j < 4; ++j) {
            int cc = col + j;
            int p = cc/9, j2 = cc - p*9;
            Pl[p*BSTR + i2*9 + j2] = uu[j];
        }
    }
    __syncthreads();

    int wv = t >> 6, l = t & 63;
    int lrow = l & 15, lhi = l >> 4;

    short8 bfr[3][3];
    #pragma unroll
    for (int ntl = 0; ntl < 3; ++ntl) {
        int n = (wv*3 + ntl)*16 + lrow;
        #pragma unroll
        for (int kk = 0; kk < 3; ++kk)
            bfr[ntl][kk] = *reinterpret_cast<const short8*>(&Pl[n*BSTR + kk*32 + lhi*8]);
    }

    f32x4 acc[6][3];
    #pragma unroll
    for (int mt = 0; mt < 6; ++mt)
        #pragma unroll
        for (int ntl = 0; ntl < 3; ++ntl)
            acc[mt][ntl] = (f32x4){0.f,0.f,0.f,0.f};

    const unsigned short* Mc = Mg + c*9216;
    #pragma unroll
    for (int mt = 0; mt < 6; ++mt) {
        short8 afr[3];
        #pragma unroll
        for (int kk = 0; kk < 3; ++kk)
            afr[kk] = *reinterpret_cast<const short8*>(Mc + (mt*16 + lrow)*96 + kk*32 + lhi*8);
        #pragma unroll
        for (int ntl = 0; ntl < 3; ++ntl) {
            f32x4 d = acc[mt][ntl];
            #pragma unroll
            for (int kk = 0; kk < 3; ++kk)
                d = __builtin_amdgcn_mfma_f32_16x16x32_bf16(afr[kk], bfr[ntl][kk], d, 0, 0, 0);
            acc[mt][ntl] = d;
        }
    }
    __syncthreads();

    float* stage = reinterpret_cast<float*>(Pl);
    #pragma unroll
    for (int pass = 0; pass < 2; ++pass) {
        if ((wv >> 1) == pass) {
            #pragma unroll
            for (int mt = 0; mt < 6; ++mt)
                #pragma unroll
                for (int ntl = 0; ntl < 3; ++ntl) {
                    int n = (wv*3 + ntl)*16 + lrow - pass*96;
                    #pragma unroll
                    for (int r = 0; r < 4; ++r) {
                        int m = mt*16 + lhi*4 + r;
                        if (m <= 80) {
                            int i = m/9, j = m - 9*i;
                            stage[i*864 + n*9 + j] = acc[mt][ntl][r];
                        }
                    }
                }
        }
        __syncthreads();
        for (int idx = t; idx < 1944; idx += 256) {
            int i = idx/216, c4 = idx - i*216;
            float4 sv = *reinterpret_cast<const float4*>(&stage[i*864 + c4*4]);
            int ga = c*S1 + (ph*9 + i)*W1 + colbase + pass*864 + c4*4;
            float4 dv = *reinterpret_cast<const float4*>(&z[ga]);
            float4 ov;
            float cr;
            cr = sv.x*INV_NZ; ov.x = dv.x + (cr > 0.f ? cr : 0.2f*cr)*dv.x;
            cr = sv.y*INV_NZ; ov.y = dv.y + (cr > 0.f ? cr : 0.2f*cr)*dv.y;
            cr = sv.z*INV_NZ; ov.z = dv.z + (cr > 0.f ? cr : 0.2f*cr)*dv.z;
            cr = sv.w*INV_NZ; ov.w = dv.w + (cr > 0.f ? cr : 0.2f*cr)*dv.w;
            *reinterpret_cast<float4*>(&out[ga]) = ov;
        }
        __syncthreads();
    }
}

extern "C" void kernel_launch(void* const* d_in, const int* in_sizes, int n_in,
                              void* d_out, int out_size, void* d_ws, size_t ws_size,
                              hipStream_t stream)
{
    (void)in_sizes; (void)n_in; (void)out_size; (void)ws_size;
    const in_t* x     = (const in_t*)d_in[0];
    const in_t* y     = (const in_t*)d_in[1];
    const in_t* z     = (const in_t*)d_in[2];
    const in_t* w_img = (const in_t*)d_in[3];
    const in_t* b_img = (const in_t*)d_in[4];
    const in_t* w_fea = (const in_t*)d_in[5];
    const in_t* b_fea = (const in_t*)d_in[6];
    out_t* out = (out_t*)d_out;

    char* ws = (char*)d_ws;
    bf16*           xq = (bf16*)          (ws + 0);          // 23,887,872
    unsigned short* yk = (unsigned short*)(ws + 23887872);   // 2,985,984
    unsigned short* xd = (unsigned short*)(ws + 26873856);   // 2,985,984
    unsigned short* Mg = (unsigned short*)(ws + 29859840);   // 1,179,648

    hipLaunchKernelGGL(k_stage1, dim3(NB_PL + NB_PX + NB_PY), dim3(256), 0, stream,
                       x, w_img, b_img, xq, y, w_fea, b_fea, yk, z, xd);
    hipLaunchKernelGGL(k_M,      dim3(576), dim3(256), 0, stream, xd, yk, Mg);
    hipLaunchKernelGGL(k_corr,   dim3(768), dim3(256), 0, stream, Mg, xq, z, out);
}

// Round 16
// 80.239 us; speedup vs baseline: 1.0332x; 1.0332x over previous
//
#include <hip/hip_runtime.h>
#include <hip/hip_bf16.h>

typedef __hip_bfloat16 bf16;
typedef float in_t;
typedef float out_t;
typedef __attribute__((ext_vector_type(8))) short short8;   // 8 bf16 MFMA operand
typedef __attribute__((ext_vector_type(4))) float f32x4;    // MFMA accumulator

#define CH    64
#define CIN1  32
#define CIN2  64
#define S1    186624   // 36*72*72
#define W1    5184     // 72*72
#define S2    23328    // 18*36*36
#define W2    1296     // 36*36
#define LDSTR 1297     // k_M LDS row stride (coprime with 32)
#define BSTR  104      // k_corr patch lds bf16 row stride
#define OSTR  136      // proj_x output tile ushort stride
#define YSTR  68       // proj_y output tile ushort stride
#define HWSTR 76       // pool LDS row stride
#define INV_NZ (1.0f/(288.0f + 1e-5f))

#define NB_PL 2304     // pool blocks (half-planes)
#define NB_PX 1458     // proj_x blocks
#define NB_PY 365      // proj_y blocks (4 wave-tiles each)
#define NBT   (NB_PL + NB_PX + NB_PY)   // 4127
#define NBR   (NBT - NB_PL)             // 1823

static __device__ __forceinline__ unsigned short f2bu(float f) {
    bf16 h = __float2bfloat16(f);
    unsigned short u;
    __builtin_memcpy(&u, &h, 2);
    return u;
}
static __device__ __forceinline__ float bu2f(unsigned short u) {
    unsigned int v = ((unsigned int)u) << 16;
    float f;
    __builtin_memcpy(&f, &v, 4);
    return f;
}

// ---- fused stage 1, Bresenham-interleaved: pool | proj_x | proj_y mixed across dispatch
__global__ __launch_bounds__(256) void k_stage1(
    const in_t* __restrict__ x, const in_t* __restrict__ wi, const in_t* __restrict__ bi,
    bf16* __restrict__ xq,
    const in_t* __restrict__ y, const in_t* __restrict__ wf, const in_t* __restrict__ bf,
    unsigned short* __restrict__ yk,
    const in_t* __restrict__ z, unsigned short* __restrict__ xd)
{
    __shared__ __align__(16) char smem[17408];
    int t = threadIdx.x;
    long long i = blockIdx.x;

    // two-level Bresenham type assignment (exact counts, unique sub-indices)
    long long pb = (i*NB_PL)/NBT;
    bool is_pool = ((i+1)*NB_PL)/NBT > pb;
    long long r  = i - pb;                       // rank among non-pool
    long long yb = (r*NB_PY)/NBR;
    bool is_py   = !is_pool && (((r+1)*NB_PY)/NBR > yb);

    if (is_pool) {
        // ---- pool half-plane: AvgPool3d k3 s2 p1 cip=False, register d-sum + LDS hw
        int bid = (int)pb;
        float* dsum = reinterpret_cast<float*>(smem);
        int c  = bid / 36;
        int rr = bid - c*36;
        int od = rr >> 1, half = rr & 1;
        int hbase = half ? 35 : 0;
        int nrows = half ? 37 : 36;
        int oh0   = half ? 18 : 0;
        int dlo = od ? 2*od - 1 : 0;
        int nd  = od ? 3 : 2;
        const float* zb = z + ((size_t)c*36 + dlo)*W1;
        for (int ii = t; ii < nrows*18; ii += 256) {
            int rw = ii / 18, q = ii - (ii/18)*18;
            int off = (hbase + rw)*18 + q;
            const float4* p0 = reinterpret_cast<const float4*>(zb);
            float4 a = p0[off], b = p0[1296 + off];
            float4 s;
            if (nd == 3) {
                float4 e = p0[2592 + off];
                s = (float4){ a.x+b.x+e.x, a.y+b.y+e.y, a.z+b.z+e.z, a.w+b.w+e.w };
            } else {
                s = (float4){ a.x+b.x, a.y+b.y, a.z+b.z, a.w+b.w };
            }
            *reinterpret_cast<float4*>(&dsum[rw*HWSTR + q*4]) = s;
        }
        __syncthreads();
        float icd = (nd == 3) ? (1.f/3.f) : 0.5f;
        unsigned short* xdp = xd + (size_t)c*S2 + (size_t)od*W2 + oh0*36;
        for (int idx = t; idx < 648; idx += 256) {
            int ohl = idx / 36, ow = idx - (idx/36)*36;
            int oh = oh0 + ohl;
            int h0 = oh ? 2*oh-1 : 0, h1 = 2*oh+1;
            int w0 = ow ? 2*ow-1 : 0, w1 = 2*ow+1;
            float s = 0.f;
            for (int h = h0; h <= h1; ++h) {
                int lr = h - hbase;
                for (int w = w0; w <= w1; ++w)
                    s += dsum[lr*HWSTR + w];
            }
            float ich = (h1 - h0) == 1 ? 0.5f : (1.f/3.f);
            float icw = (w1 - w0) == 1 ? 0.5f : (1.f/3.f);
            xdp[idx] = f2bu(s * icd * ich * icw);
        }
    } else if (!is_py) {
        // ---- proj_x: xq(64,S1) = Wi(64,32) x x(32,S1) + bi, bf16 out
        int gs0 = (int)(r - yb)*128;
        int l = t & 63, wv = t >> 6;
        int lcol = l & 15, loct = l >> 4;

        ushort4 rr4[2][4];
        #pragma unroll
        for (int mt = 0; mt < 2; ++mt) {
            int scol = gs0 + (wv*2 + mt)*16 + lcol;
            union { short8 v; unsigned short u[8]; } af;
            #pragma unroll
            for (int j = 0; j < 8; ++j)
                af.u[j] = f2bu(x[(size_t)(loct*8 + j)*S1 + scol]);
            #pragma unroll
            for (int og = 0; og < 4; ++og) {
                int o = og*16 + lcol;
                union { short8 v; unsigned short u[8]; } wfr;
                float4 a  = *reinterpret_cast<const float4*>(&wi[o*CIN1 + loct*8]);
                float4 bq = *reinterpret_cast<const float4*>(&wi[o*CIN1 + loct*8 + 4]);
                wfr.u[0]=f2bu(a.x);  wfr.u[1]=f2bu(a.y);
                wfr.u[2]=f2bu(a.z);  wfr.u[3]=f2bu(a.w);
                wfr.u[4]=f2bu(bq.x); wfr.u[5]=f2bu(bq.y);
                wfr.u[6]=f2bu(bq.z); wfr.u[7]=f2bu(bq.w);
                float bo = bi[o];
                f32x4 d = { bo, bo, bo, bo };
                d = __builtin_amdgcn_mfma_f32_16x16x32_bf16(af.v, wfr.v, d, 0, 0, 0);
                rr4[mt][og] = (ushort4){ f2bu(d[0]), f2bu(d[1]), f2bu(d[2]), f2bu(d[3]) };
            }
        }
        unsigned short* ot = reinterpret_cast<unsigned short*>(smem);  // 64 x OSTR
        #pragma unroll
        for (int mt = 0; mt < 2; ++mt)
            #pragma unroll
            for (int og = 0; og < 4; ++og)
                *reinterpret_cast<ushort4*>(
                    &ot[(og*16 + lcol)*OSTR + wv*32 + mt*16 + loct*4]) = rr4[mt][og];
        __syncthreads();
        #pragma unroll
        for (int j = 0; j < 4; ++j) {
            int row = wv*16 + j*4 + (l >> 4);
            int c8  = l & 15;
            uint4 v = *reinterpret_cast<const uint4*>(&ot[row*OSTR + c8*8]);
            *reinterpret_cast<uint4*>(
                (unsigned short*)xq + (size_t)row*S1 + gs0 + c8*8) = v;
        }
    } else {
        // ---- proj_y: yk(64,S2) = Wf(64,64) x y(64,S2) + bf, bf16 out
        int pyb   = (int)yb;
        int sblk0 = pyb*64;
        int wv = t >> 6, l = t & 63;
        int lcol = l & 15, loct = l >> 4;
        int tile = pyb*4 + wv;
        unsigned short* ot = reinterpret_cast<unsigned short*>(smem);   // 64 x YSTR
        if (tile < 1458) {
            int s0 = tile*16;
            union { short8 v; unsigned short u[8]; } af[2];
            #pragma unroll
            for (int kk = 0; kk < 2; ++kk)
                #pragma unroll
                for (int j = 0; j < 8; ++j)
                    af[kk].u[j] = f2bu(y[(size_t)(kk*32 + loct*8 + j)*S2 + s0 + lcol]);
            #pragma unroll
            for (int og = 0; og < 4; ++og) {
                int o = og*16 + lcol;
                union { short8 v; unsigned short u[8]; } wfr[2];
                #pragma unroll
                for (int kk = 0; kk < 2; ++kk) {
                    float4 a  = *reinterpret_cast<const float4*>(&wf[o*CIN2 + kk*32 + loct*8]);
                    float4 bq = *reinterpret_cast<const float4*>(&wf[o*CIN2 + kk*32 + loct*8 + 4]);
                    wfr[kk].u[0]=f2bu(a.x);  wfr[kk].u[1]=f2bu(a.y);
                    wfr[kk].u[2]=f2bu(a.z);  wfr[kk].u[3]=f2bu(a.w);
                    wfr[kk].u[4]=f2bu(bq.x); wfr[kk].u[5]=f2bu(bq.y);
                    wfr[kk].u[6]=f2bu(bq.z); wfr[kk].u[7]=f2bu(bq.w);
                }
                float bo = bf[o];
                f32x4 d = { bo, bo, bo, bo };
                d = __builtin_amdgcn_mfma_f32_16x16x32_bf16(af[0].v, wfr[0].v, d, 0, 0, 0);
                d = __builtin_amdgcn_mfma_f32_16x16x32_bf16(af[1].v, wfr[1].v, d, 0, 0, 0);
                ushort4 r4 = { f2bu(d[0]), f2bu(d[1]), f2bu(d[2]), f2bu(d[3]) };
                *reinterpret_cast<ushort4*>(&ot[(og*16 + lcol)*YSTR + wv*16 + loct*4]) = r4;
            }
        }
        __syncthreads();
        #pragma unroll
        for (int j = 0; j < 4; ++j) {
            int row = wv*16 + j*4 + (l >> 4);
            int c4  = l & 15;
            int s   = sblk0 + c4*4;
            if (s < S2) {
                ushort4 v = *reinterpret_cast<const ushort4*>(&ot[row*YSTR + c4*4]);
                *reinterpret_cast<ushort4*>(&yk[(size_t)row*S2 + s]) = v;
            }
        }
    }
}

// ---- M[c,k1,k2] = sum_m Uxd[c,k1,m]*Uy[c,k2,m]; bf16 in, bf16 zero-padded [c][96][96] out
__global__ __launch_bounds__(256) void k_M(
    const unsigned short* __restrict__ xd, const unsigned short* __restrict__ yk,
    unsigned short* __restrict__ Mg)
{
    __shared__ float xl[3*LDSTR];
    __shared__ float yl[3*LDSTR];
    int b = blockIdx.x;
    int c = b / 9, r = b - c*9;
    int g = r / 3, h = r - g*3;
    int t = threadIdx.x;
    int t1 = t / 27, t2 = t - (t/27)*27;
    int offx[3];
    #pragma unroll
    for (int a = 0; a < 3; ++a) {
        int kl = t1*3 + a;
        offx[a] = (kl/9)*LDSTR + (kl - (kl/9)*9);
    }
    int offy = (t2/9)*LDSTR + (t2 - (t2/9)*9);
    float acc[3] = {};
    for (int ph2 = 0; ph2 < 2; ++ph2) {
        __syncthreads();
        for (int idx = t; idx < 3*W2; idx += 256) {
            int rr = idx / W2, col = idx - rr*W2;
            xl[rr*LDSTR + col] = bu2f(xd[c*S2 + (ph2*9 + g*3 + rr)*W2 + col]);
            yl[rr*LDSTR + col] = bu2f(yk[c*S2 + (ph2*9 + h*3 + rr)*W2 + col]);
        }
        __syncthreads();
        if (t < 243) {
            for (int m = 0; m < 144; ++m) {
                int cb = m*9;
                float yv = yl[cb + offy];
                #pragma unroll
                for (int a = 0; a < 3; ++a)
                    acc[a] += xl[cb + offx[a]] * yv;
            }
        }
    }
    if (t < 243) {
        #pragma unroll
        for (int a = 0; a < 3; ++a) {
            int k1 = g*27 + t1*3 + a;
            Mg[c*9216 + k1*96 + (h*27 + t2)] = f2bu(acc[a]);
        }
    }
    if (r == 0) {
        for (int idx = t; idx < 2655; idx += 256) {
            int row, col;
            if (idx < 1440) { int q = idx/96; row = 81 + q; col = idx - q*96; }
            else { int j = idx - 1440; int q = j/15; row = q; col = 81 + (j - q*15); }
            Mg[c*9216 + row*96 + col] = 0;
        }
    }
}

// ---- MFMA corr: per (channel, 192-patch chunk): C(96x192) = Mg(96x96,bf16) x Uxq^T
__global__ __launch_bounds__(256, 4) void k_corr(
    const unsigned short* __restrict__ Mg, const bf16* __restrict__ xq,
    const in_t* __restrict__ z, out_t* __restrict__ out)
{
    __shared__ __align__(16) unsigned short Pl[192*BSTR];   // 39936 B -> 4 blocks/CU
    int bid = blockIdx.x;
    int c   = bid / 12;
    int rem = bid - c*12;
    int ph  = rem / 3;
    int ck  = rem - ph*3;
    int colbase = ck*1728;
    int t = threadIdx.x;

    for (int idx = t; idx < 192*15; idx += 256) {
        int r = idx/15;
        Pl[r*BSTR + 81 + (idx - r*15)] = 0;
    }
    const unsigned short* xqu =
        (const unsigned short*)(xq + (size_t)c*S1 + (size_t)(ph*9)*W1 + colbase);
    for (int idx = t; idx < 3888; idx += 256) {
        int i2 = idx / 432, v4 = idx - i2*432;
        ushort4 vv = *reinterpret_cast<const ushort4*>(xqu + (size_t)i2*W1 + v4*4);
        int col = v4*4;
        unsigned short uu[4] = {vv.x, vv.y, vv.z, vv.w};
        #pragma unroll
        for (int j = 0; j < 4; ++j) {
            int cc = col + j;
            int p = cc/9, j2 = cc - p*9;
            Pl[p*BSTR + i2*9 + j2] = uu[j];
        }
    }
    __syncthreads();

    int wv = t >> 6, l = t & 63;
    int lrow = l & 15, lhi = l >> 4;

    short8 bfr[3][3];
    #pragma unroll
    for (int ntl = 0; ntl < 3; ++ntl) {
        int n = (wv*3 + ntl)*16 + lrow;
        #pragma unroll
        for (int kk = 0; kk < 3; ++kk)
            bfr[ntl][kk] = *reinterpret_cast<const short8*>(&Pl[n*BSTR + kk*32 + lhi*8]);
    }

    f32x4 acc[6][3];
    #pragma unroll
    for (int mt = 0; mt < 6; ++mt)
        #pragma unroll
        for (int ntl = 0; ntl < 3; ++ntl)
            acc[mt][ntl] = (f32x4){0.f,0.f,0.f,0.f};

    const unsigned short* Mc = Mg + c*9216;
    #pragma unroll
    for (int mt = 0; mt < 6; ++mt) {
        short8 afr[3];
        #pragma unroll
        for (int kk = 0; kk < 3; ++kk)
            afr[kk] = *reinterpret_cast<const short8*>(Mc + (mt*16 + lrow)*96 + kk*32 + lhi*8);
        #pragma unroll
        for (int ntl = 0; ntl < 3; ++ntl) {
            f32x4 d = acc[mt][ntl];
            #pragma unroll
            for (int kk = 0; kk < 3; ++kk)
                d = __builtin_amdgcn_mfma_f32_16x16x32_bf16(afr[kk], bfr[ntl][kk], d, 0, 0, 0);
            acc[mt][ntl] = d;
        }
    }
    __syncthreads();

    float* stage = reinterpret_cast<float*>(Pl);
    #pragma unroll
    for (int pass = 0; pass < 2; ++pass) {
        if ((wv >> 1) == pass) {
            #pragma unroll
            for (int mt = 0; mt < 6; ++mt)
                #pragma unroll
                for (int ntl = 0; ntl < 3; ++ntl) {
                    int n = (wv*3 + ntl)*16 + lrow - pass*96;
                    #pragma unroll
                    for (int r = 0; r < 4; ++r) {
                        int m = mt*16 + lhi*4 + r;
                        if (m <= 80) {
                            int i = m/9, j = m - 9*i;
                            stage[i*864 + n*9 + j] = acc[mt][ntl][r];
                        }
                    }
                }
        }
        __syncthreads();
        for (int idx = t; idx < 1944; idx += 256) {
            int i = idx/216, c4 = idx - i*216;
            float4 sv = *reinterpret_cast<const float4*>(&stage[i*864 + c4*4]);
            int ga = c*S1 + (ph*9 + i)*W1 + colbase + pass*864 + c4*4;
            float4 dv = *reinterpret_cast<const float4*>(&z[ga]);
            float4 ov;
            float cr;
            cr = sv.x*INV_NZ; ov.x = dv.x + (cr > 0.f ? cr : 0.2f*cr)*dv.x;
            cr = sv.y*INV_NZ; ov.y = dv.y + (cr > 0.f ? cr : 0.2f*cr)*dv.y;
            cr = sv.z*INV_NZ; ov.z = dv.z + (cr > 0.f ? cr : 0.2f*cr)*dv.z;
            cr = sv.w*INV_NZ; ov.w = dv.w + (cr > 0.f ? cr : 0.2f*cr)*dv.w;
            *reinterpret_cast<float4*>(&out[ga]) = ov;
        }
        __syncthreads();
    }
}

extern "C" void kernel_launch(void* const* d_in, const int* in_sizes, int n_in,
                              void* d_out, int out_size, void* d_ws, size_t ws_size,
                              hipStream_t stream)
{
    (void)in_sizes; (void)n_in; (void)out_size; (void)ws_size;
    const in_t* x     = (const in_t*)d_in[0];
    const in_t* y     = (const in_t*)d_in[1];
    const in_t* z     = (const in_t*)d_in[2];
    const in_t* w_img = (const in_t*)d_in[3];
    const in_t* b_img = (const in_t*)d_in[4];
    const in_t* w_fea = (const in_t*)d_in[5];
    const in_t* b_fea = (const in_t*)d_in[6];
    out_t* out = (out_t*)d_out;

    char* ws = (char*)d_ws;
    bf16*           xq = (bf16*)          (ws + 0);          // 23,887,872
    unsigned short* yk = (unsigned short*)(ws + 23887872);   // 2,985,984
    unsigned short* xd = (unsigned short*)(ws + 26873856);   // 2,985,984
    unsigned short* Mg = (unsigned short*)(ws + 29859840);   // 1,179,648

    hipLaunchKernelGGL(k_stage1, dim3(NBT), dim3(256), 0, stream,
                       x, w_img, b_img, xq, y, w_fea, b_fea, yk, z, xd);
    hipLaunchKernelGGL(k_M,      dim3(576), dim3(256), 0, stream, xd, yk, Mg);
    hipLaunchKernelGGL(k_corr,   dim3(768), dim3(256), 0, stream, Mg, xq, z, out);
}

// Round 17
// 66.280 us; speedup vs baseline: 1.2508x; 1.2106x over previous
//
#include <hip/hip_runtime.h>
#include <hip/hip_bf16.h>

typedef __hip_bfloat16 bf16;
typedef float in_t;
typedef float out_t;
typedef __attribute__((ext_vector_type(8))) short short8;   // 8 bf16 MFMA operand
typedef __attribute__((ext_vector_type(4))) float f32x4;    // MFMA accumulator

#define CH    64
#define CIN1  32
#define CIN2  64
#define S1    186624   // 36*72*72
#define W1    5184     // 72*72
#define S2    23328    // 18*36*36
#define W2    1296     // 36*36
#define BSTR  104      // k_corr patch lds bf16 row stride
#define ASTR  104      // k_M operand lds bf16 row stride (b128-aligned)
#define OSTR  136      // proj_x output tile ushort stride
#define YSTR  68       // proj_y output tile ushort stride
#define HWSTR 76       // pool LDS row stride
#define INV_NZ (1.0f/(288.0f + 1e-5f))

#define NB_PL 2304     // pool blocks (half-planes)
#define NB_PX 1458     // proj_x blocks
#define NB_PY 365      // proj_y blocks (4 wave-tiles each)
#define NBT   (NB_PL + NB_PX + NB_PY)   // 4127
#define NBR   (NBT - NB_PL)             // 1823

static __device__ __forceinline__ unsigned short f2bu(float f) {
    bf16 h = __float2bfloat16(f);
    unsigned short u;
    __builtin_memcpy(&u, &h, 2);
    return u;
}

// ---- fused stage 1, Bresenham-interleaved: pool | proj_x | proj_y mixed across dispatch
__global__ __launch_bounds__(256) void k_stage1(
    const in_t* __restrict__ x, const in_t* __restrict__ wi, const in_t* __restrict__ bi,
    bf16* __restrict__ xq,
    const in_t* __restrict__ y, const in_t* __restrict__ wf, const in_t* __restrict__ bf,
    unsigned short* __restrict__ yk,
    const in_t* __restrict__ z, unsigned short* __restrict__ xd)
{
    __shared__ __align__(16) char smem[17408];
    int t = threadIdx.x;
    long long i = blockIdx.x;

    long long pb = (i*NB_PL)/NBT;
    bool is_pool = ((i+1)*NB_PL)/NBT > pb;
    long long r  = i - pb;
    long long yb = (r*NB_PY)/NBR;
    bool is_py   = !is_pool && (((r+1)*NB_PY)/NBR > yb);

    if (is_pool) {
        int bid = (int)pb;
        float* dsum = reinterpret_cast<float*>(smem);
        int c  = bid / 36;
        int rr = bid - c*36;
        int od = rr >> 1, half = rr & 1;
        int hbase = half ? 35 : 0;
        int nrows = half ? 37 : 36;
        int oh0   = half ? 18 : 0;
        int dlo = od ? 2*od - 1 : 0;
        int nd  = od ? 3 : 2;
        const float* zb = z + ((size_t)c*36 + dlo)*W1;
        for (int ii = t; ii < nrows*18; ii += 256) {
            int rw = ii / 18, q = ii - (ii/18)*18;
            int off = (hbase + rw)*18 + q;
            const float4* p0 = reinterpret_cast<const float4*>(zb);
            float4 a = p0[off], b = p0[1296 + off];
            float4 s;
            if (nd == 3) {
                float4 e = p0[2592 + off];
                s = (float4){ a.x+b.x+e.x, a.y+b.y+e.y, a.z+b.z+e.z, a.w+b.w+e.w };
            } else {
                s = (float4){ a.x+b.x, a.y+b.y, a.z+b.z, a.w+b.w };
            }
            *reinterpret_cast<float4*>(&dsum[rw*HWSTR + q*4]) = s;
        }
        __syncthreads();
        float icd = (nd == 3) ? (1.f/3.f) : 0.5f;
        unsigned short* xdp = xd + (size_t)c*S2 + (size_t)od*W2 + oh0*36;
        for (int idx = t; idx < 648; idx += 256) {
            int ohl = idx / 36, ow = idx - (idx/36)*36;
            int oh = oh0 + ohl;
            int h0 = oh ? 2*oh-1 : 0, h1 = 2*oh+1;
            int w0 = ow ? 2*ow-1 : 0, w1 = 2*ow+1;
            float s = 0.f;
            for (int h = h0; h <= h1; ++h) {
                int lr = h - hbase;
                for (int w = w0; w <= w1; ++w)
                    s += dsum[lr*HWSTR + w];
            }
            float ich = (h1 - h0) == 1 ? 0.5f : (1.f/3.f);
            float icw = (w1 - w0) == 1 ? 0.5f : (1.f/3.f);
            xdp[idx] = f2bu(s * icd * ich * icw);
        }
    } else if (!is_py) {
        // ---- proj_x: xq(64,S1) = Wi(64,32) x x(32,S1) + bi, bf16 out
        int gs0 = (int)(r - yb)*128;
        int l = t & 63, wv = t >> 6;
        int lcol = l & 15, loct = l >> 4;

        ushort4 rr4[2][4];
        #pragma unroll
        for (int mt = 0; mt < 2; ++mt) {
            int scol = gs0 + (wv*2 + mt)*16 + lcol;
            union { short8 v; unsigned short u[8]; } af;
            #pragma unroll
            for (int j = 0; j < 8; ++j)
                af.u[j] = f2bu(x[(size_t)(loct*8 + j)*S1 + scol]);
            #pragma unroll
            for (int og = 0; og < 4; ++og) {
                int o = og*16 + lcol;
                union { short8 v; unsigned short u[8]; } wfr;
                float4 a  = *reinterpret_cast<const float4*>(&wi[o*CIN1 + loct*8]);
                float4 bq = *reinterpret_cast<const float4*>(&wi[o*CIN1 + loct*8 + 4]);
                wfr.u[0]=f2bu(a.x);  wfr.u[1]=f2bu(a.y);
                wfr.u[2]=f2bu(a.z);  wfr.u[3]=f2bu(a.w);
                wfr.u[4]=f2bu(bq.x); wfr.u[5]=f2bu(bq.y);
                wfr.u[6]=f2bu(bq.z); wfr.u[7]=f2bu(bq.w);
                float bo = bi[o];
                f32x4 d = { bo, bo, bo, bo };
                d = __builtin_amdgcn_mfma_f32_16x16x32_bf16(af.v, wfr.v, d, 0, 0, 0);
                rr4[mt][og] = (ushort4){ f2bu(d[0]), f2bu(d[1]), f2bu(d[2]), f2bu(d[3]) };
            }
        }
        unsigned short* ot = reinterpret_cast<unsigned short*>(smem);  // 64 x OSTR
        #pragma unroll
        for (int mt = 0; mt < 2; ++mt)
            #pragma unroll
            for (int og = 0; og < 4; ++og)
                *reinterpret_cast<ushort4*>(
                    &ot[(og*16 + lcol)*OSTR + wv*32 + mt*16 + loct*4]) = rr4[mt][og];
        __syncthreads();
        #pragma unroll
        for (int j = 0; j < 4; ++j) {
            int row = wv*16 + j*4 + (l >> 4);
            int c8  = l & 15;
            uint4 v = *reinterpret_cast<const uint4*>(&ot[row*OSTR + c8*8]);
            *reinterpret_cast<uint4*>(
                (unsigned short*)xq + (size_t)row*S1 + gs0 + c8*8) = v;
        }
    } else {
        // ---- proj_y: yk(64,S2) = Wf(64,64) x y(64,S2) + bf, bf16 out
        int pyb   = (int)yb;
        int sblk0 = pyb*64;
        int wv = t >> 6, l = t & 63;
        int lcol = l & 15, loct = l >> 4;
        int tile = pyb*4 + wv;
        unsigned short* ot = reinterpret_cast<unsigned short*>(smem);   // 64 x YSTR
        if (tile < 1458) {
            int s0 = tile*16;
            union { short8 v; unsigned short u[8]; } af[2];
            #pragma unroll
            for (int kk = 0; kk < 2; ++kk)
                #pragma unroll
                for (int j = 0; j < 8; ++j)
                    af[kk].u[j] = f2bu(y[(size_t)(kk*32 + loct*8 + j)*S2 + s0 + lcol]);
            #pragma unroll
            for (int og = 0; og < 4; ++og) {
                int o = og*16 + lcol;
                union { short8 v; unsigned short u[8]; } wfr[2];
                #pragma unroll
                for (int kk = 0; kk < 2; ++kk) {
                    float4 a  = *reinterpret_cast<const float4*>(&wf[o*CIN2 + kk*32 + loct*8]);
                    float4 bq = *reinterpret_cast<const float4*>(&wf[o*CIN2 + kk*32 + loct*8 + 4]);
                    wfr[kk].u[0]=f2bu(a.x);  wfr[kk].u[1]=f2bu(a.y);
                    wfr[kk].u[2]=f2bu(a.z);  wfr[kk].u[3]=f2bu(a.w);
                    wfr[kk].u[4]=f2bu(bq.x); wfr[kk].u[5]=f2bu(bq.y);
                    wfr[kk].u[6]=f2bu(bq.z); wfr[kk].u[7]=f2bu(bq.w);
                }
                float bo = bf[o];
                f32x4 d = { bo, bo, bo, bo };
                d = __builtin_amdgcn_mfma_f32_16x16x32_bf16(af[0].v, wfr[0].v, d, 0, 0, 0);
                d = __builtin_amdgcn_mfma_f32_16x16x32_bf16(af[1].v, wfr[1].v, d, 0, 0, 0);
                ushort4 r4 = { f2bu(d[0]), f2bu(d[1]), f2bu(d[2]), f2bu(d[3]) };
                *reinterpret_cast<ushort4*>(&ot[(og*16 + lcol)*YSTR + wv*16 + loct*4]) = r4;
            }
        }
        __syncthreads();
        #pragma unroll
        for (int j = 0; j < 4; ++j) {
            int row = wv*16 + j*4 + (l >> 4);
            int c4  = l & 15;
            int s   = sblk0 + c4*4;
            if (s < S2) {
                ushort4 v = *reinterpret_cast<const ushort4*>(&ot[row*YSTR + c4*4]);
                *reinterpret_cast<ushort4*>(&yk[(size_t)row*S2 + s]) = v;
            }
        }
    }
}

// ---- MFMA k_M: per channel, M(96x96) = Uxd_pad(96x288) x Uy_pad^T, bf16 out
// m permuted as m' = pw2_local*2 + ph2; 3 K-chunks of 96; rows 81..95 zero -> auto-pad
// grid = 64 blocks (1/channel) x 256 threads (4 waves, 2x2 tile grid of 48x48)
__global__ __launch_bounds__(256) void k_M(
    const unsigned short* __restrict__ xd, const unsigned short* __restrict__ yk,
    unsigned short* __restrict__ Mg)
{
    __shared__ __align__(16) unsigned short Al[96*ASTR];
    __shared__ __align__(16) unsigned short Bl[96*ASTR];
    int c = blockIdx.x;
    int t = threadIdx.x;
    int l = t & 63, wv = t >> 6;
    int lcol = l & 15, lhi = l >> 4;
    int wr = wv >> 1, wc = wv & 1;

    // zero rows 81..95 once (stage loop only writes rows 0..80)
    for (int idx = t; idx < 15*ASTR; idx += 256) {
        Al[81*ASTR + idx] = 0;
        Bl[81*ASTR + idx] = 0;
    }

    f32x4 acc[3][3];
    #pragma unroll
    for (int a = 0; a < 3; ++a)
        #pragma unroll
        for (int b = 0; b < 3; ++b)
            acc[a][b] = (f32x4){0.f,0.f,0.f,0.f};

    const unsigned short* xc = xd + (size_t)c*S2;
    const unsigned short* yc = yk + (size_t)c*S2;

    for (int q = 0; q < 3; ++q) {
        __syncthreads();
        // stage chunk q: src rows r18 (18), cols 432q .. 432q+431 (ushort4)
        for (int idx = t; idx < 1944; idx += 256) {
            int r18 = idx / 108, u4 = idx - r18*108;
            int srcoff = r18*W2 + q*432 + u4*4;
            ushort4 va = *reinterpret_cast<const ushort4*>(xc + srcoff);
            ushort4 vb = *reinterpret_cast<const ushort4*>(yc + srcoff);
            int ph2 = r18 / 9, i2 = r18 - ph2*9;
            unsigned short ua[4] = {va.x, va.y, va.z, va.w};
            unsigned short ub[4] = {vb.x, vb.y, vb.z, vb.w};
            #pragma unroll
            for (int j = 0; j < 4; ++j) {
                int cc  = u4*4 + j;            // 0..431 within chunk
                int pw2 = cc / 9, j2 = cc - pw2*9;
                int row = i2*9 + j2;           // k index 0..80
                int mp  = pw2*2 + ph2;         // 0..95
                Al[row*ASTR + mp] = ua[j];
                Bl[row*ASTR + mp] = ub[j];
            }
        }
        __syncthreads();
        #pragma unroll
        for (int kk = 0; kk < 3; ++kk) {
            short8 afr[3], bfr[3];
            #pragma unroll
            for (int a = 0; a < 3; ++a)
                afr[a] = *reinterpret_cast<const short8*>(
                    &Al[(wr*48 + a*16 + lcol)*ASTR + kk*32 + lhi*8]);
            #pragma unroll
            for (int b = 0; b < 3; ++b)
                bfr[b] = *reinterpret_cast<const short8*>(
                    &Bl[(wc*48 + b*16 + lcol)*ASTR + kk*32 + lhi*8]);
            #pragma unroll
            for (int a = 0; a < 3; ++a)
                #pragma unroll
                for (int b = 0; b < 3; ++b)
                    acc[a][b] = __builtin_amdgcn_mfma_f32_16x16x32_bf16(
                        afr[a], bfr[b], acc[a][b], 0, 0, 0);
        }
    }
    // write M[96][96] bf16: D row=(lhi*4+rr) -> k1, col=lcol -> k2 within tile
    unsigned short* Mc = Mg + (size_t)c*9216;
    #pragma unroll
    for (int a = 0; a < 3; ++a)
        #pragma unroll
        for (int b = 0; b < 3; ++b)
            #pragma unroll
            for (int rr = 0; rr < 4; ++rr) {
                int k1 = wr*48 + a*16 + lhi*4 + rr;
                int k2 = wc*48 + b*16 + lcol;
                Mc[k1*96 + k2] = f2bu(acc[a][b][rr]);
            }
}

// ---- MFMA corr: per (channel, 192-patch chunk): C(96x192) = Mg(96x96,bf16) x Uxq^T
__global__ __launch_bounds__(256, 4) void k_corr(
    const unsigned short* __restrict__ Mg, const bf16* __restrict__ xq,
    const in_t* __restrict__ z, out_t* __restrict__ out)
{
    __shared__ __align__(16) unsigned short Pl[192*BSTR];   // 39936 B -> 4 blocks/CU
    int bid = blockIdx.x;
    int c   = bid / 12;
    int rem = bid - c*12;
    int ph  = rem / 3;
    int ck  = rem - ph*3;
    int colbase = ck*1728;
    int t = threadIdx.x;

    for (int idx = t; idx < 192*15; idx += 256) {
        int r = idx/15;
        Pl[r*BSTR + 81 + (idx - r*15)] = 0;
    }
    const unsigned short* xqu =
        (const unsigned short*)(xq + (size_t)c*S1 + (size_t)(ph*9)*W1 + colbase);
    for (int idx = t; idx < 3888; idx += 256) {
        int i2 = idx / 432, v4 = idx - i2*432;
        ushort4 vv = *reinterpret_cast<const ushort4*>(xqu + (size_t)i2*W1 + v4*4);
        int col = v4*4;
        unsigned short uu[4] = {vv.x, vv.y, vv.z, vv.w};
        #pragma unroll
        for (int j = 0; j < 4; ++j) {
            int cc = col + j;
            int p = cc/9, j2 = cc - p*9;
            Pl[p*BSTR + i2*9 + j2] = uu[j];
        }
    }
    __syncthreads();

    int wv = t >> 6, l = t & 63;
    int lrow = l & 15, lhi = l >> 4;

    short8 bfr[3][3];
    #pragma unroll
    for (int ntl = 0; ntl < 3; ++ntl) {
        int n = (wv*3 + ntl)*16 + lrow;
        #pragma unroll
        for (int kk = 0; kk < 3; ++kk)
            bfr[ntl][kk] = *reinterpret_cast<const short8*>(&Pl[n*BSTR + kk*32 + lhi*8]);
    }

    f32x4 acc[6][3];
    #pragma unroll
    for (int mt = 0; mt < 6; ++mt)
        #pragma unroll
        for (int ntl = 0; ntl < 3; ++ntl)
            acc[mt][ntl] = (f32x4){0.f,0.f,0.f,0.f};

    const unsigned short* Mc = Mg + c*9216;
    #pragma unroll
    for (int mt = 0; mt < 6; ++mt) {
        short8 afr[3];
        #pragma unroll
        for (int kk = 0; kk < 3; ++kk)
            afr[kk] = *reinterpret_cast<const short8*>(Mc + (mt*16 + lrow)*96 + kk*32 + lhi*8);
        #pragma unroll
        for (int ntl = 0; ntl < 3; ++ntl) {
            f32x4 d = acc[mt][ntl];
            #pragma unroll
            for (int kk = 0; kk < 3; ++kk)
                d = __builtin_amdgcn_mfma_f32_16x16x32_bf16(afr[kk], bfr[ntl][kk], d, 0, 0, 0);
            acc[mt][ntl] = d;
        }
    }
    __syncthreads();

    float* stage = reinterpret_cast<float*>(Pl);
    #pragma unroll
    for (int pass = 0; pass < 2; ++pass) {
        if ((wv >> 1) == pass) {
            #pragma unroll
            for (int mt = 0; mt < 6; ++mt)
                #pragma unroll
                for (int ntl = 0; ntl < 3; ++ntl) {
                    int n = (wv*3 + ntl)*16 + lrow - pass*96;
                    #pragma unroll
                    for (int r = 0; r < 4; ++r) {
                        int m = mt*16 + lhi*4 + r;
                        if (m <= 80) {
                            int i = m/9, j = m - 9*i;
                            stage[i*864 + n*9 + j] = acc[mt][ntl][r];
                        }
                    }
                }
        }
        __syncthreads();
        for (int idx = t; idx < 1944; idx += 256) {
            int i = idx/216, c4 = idx - i*216;
            float4 sv = *reinterpret_cast<const float4*>(&stage[i*864 + c4*4]);
            int ga = c*S1 + (ph*9 + i)*W1 + colbase + pass*864 + c4*4;
            float4 dv = *reinterpret_cast<const float4*>(&z[ga]);
            float4 ov;
            float cr;
            cr = sv.x*INV_NZ; ov.x = dv.x + (cr > 0.f ? cr : 0.2f*cr)*dv.x;
            cr = sv.y*INV_NZ; ov.y = dv.y + (cr > 0.f ? cr : 0.2f*cr)*dv.y;
            cr = sv.z*INV_NZ; ov.z = dv.z + (cr > 0.f ? cr : 0.2f*cr)*dv.z;
            cr = sv.w*INV_NZ; ov.w = dv.w + (cr > 0.f ? cr : 0.2f*cr)*dv.w;
            *reinterpret_cast<float4*>(&out[ga]) = ov;
        }
        __syncthreads();
    }
}

extern "C" void kernel_launch(void* const* d_in, const int* in_sizes, int n_in,
                              void* d_out, int out_size, void* d_ws, size_t ws_size,
                              hipStream_t stream)
{
    (void)in_sizes; (void)n_in; (void)out_size; (void)ws_size;
    const in_t* x     = (const in_t*)d_in[0];
    const in_t* y     = (const in_t*)d_in[1];
    const in_t* z     = (const in_t*)d_in[2];
    const in_t* w_img = (const in_t*)d_in[3];
    const in_t* b_img = (const in_t*)d_in[4];
    const in_t* w_fea = (const in_t*)d_in[5];
    const in_t* b_fea = (const in_t*)d_in[6];
    out_t* out = (out_t*)d_out;

    char* ws = (char*)d_ws;
    bf16*           xq = (bf16*)          (ws + 0);          // 23,887,872
    unsigned short* yk = (unsigned short*)(ws + 23887872);   // 2,985,984
    unsigned short* xd = (unsigned short*)(ws + 26873856);   // 2,985,984
    unsigned short* Mg = (unsigned short*)(ws + 29859840);   // 1,179,648

    hipLaunchKernelGGL(k_stage1, dim3(NBT), dim3(256), 0, stream,
                       x, w_img, b_img, xq, y, w_fea, b_fea, yk, z, xd);
    hipLaunchKernelGGL(k_M,      dim3(64),  dim3(256), 0, stream, xd, yk, Mg);
    hipLaunchKernelGGL(k_corr,   dim3(768), dim3(256), 0, stream, Mg, xq, z, out);
}